// Round 1
// baseline (4179.751 us; speedup 1.0000x reference)
//
#include <hip/hip_runtime.h>
#include <hip/hip_bf16.h>

// CTRNN: T=1000, B=256, I=128, N=512, ALPHA=0.2
// d_in: x[1000,256,128] f32, h0[256,512] f32, W_in[512,128] f32, b_in[512] f32, W_hh[512,512] f32
// d_out: output[1000,256,512] f32 ++ hidden[256,512] f32
//
//  pack_kernel : W_hh -> bf16 MFMA-A-fragment layout (512KB); W_in -> hi/lo bf16 frags in d_ws
//  xproj_kernel: xproj = x @ W_in^T + b_in via 3-term split-bf16 MFMA, written INTO d_out
//                (R2: paired-g + LDS transpose -> 1KB full-line coalesced stores; float4 x loads;
//                 2 M-tiles/wave halves WinHi/Lo L2 re-read traffic)
//  scan_kernel : 16 WGs x 512 threads (8 waves). Wave owns 4 n-strips: 3 in VGPR (192 regs),
//                1 in LDS (8 strips = 128KB).
//                (R2: raw s_barrier + lgkmcnt(0)-only -- the compiler's __syncthreads vmcnt(0)
//                 drain was putting store-ack + load-residual latency on the critical path
//                 2000x; only the LDS pack buffer needs barrier ordering. h stores are
//                 non-temporal and issued after the barrier.)

typedef __bf16 bf16;
typedef __bf16 bf16x8 __attribute__((ext_vector_type(8)));
typedef float floatx4 __attribute__((ext_vector_type(4)));
typedef unsigned short u16;
typedef u16 u16x4 __attribute__((ext_vector_type(4)));

#define T_STEPS 1000
#define BATCH 256
#define NDIM 512
#define IDIM 128

// ---------------- Phase 0: pack weights into fragment layout ----------------
// Whpack entry e (16B): g=e>>10 (0..31), s=(e>>6)&15, lane=e&63
//   holds W_hh[16g + (lane&15)][32s + 8*(lane>>4) + j], j=0..7 (bf16)
// Win pack entry e2 (16B): g=e2>>8 (0..31), s=(e2>>6)&3, lane=e2&63
//   holds W_in[16g + (lane&15)][32s + 8*(lane>>4) + j]  (hi and lo = residual)
__global__ void pack_kernel(const float* __restrict__ W_hh,
                            const float* __restrict__ W_in,
                            bf16x8* __restrict__ Whpack,
                            bf16x8* __restrict__ WinHi,
                            bf16x8* __restrict__ WinLo) {
    int e = blockIdx.x * 256 + threadIdx.x;
    if (e < 32768) {
        int g = e >> 10, s = (e >> 6) & 15, lane = e & 63;
        int n = 16 * g + (lane & 15);
        int k = 32 * s + 8 * (lane >> 4);
        const float* src = W_hh + n * 512 + k;
        bf16x8 v;
#pragma unroll
        for (int j = 0; j < 8; j++) v[j] = (bf16)src[j];
        Whpack[e] = v;
    } else {
        int e2 = e - 32768;
        if (e2 < 8192) {
            int g = e2 >> 8, s = (e2 >> 6) & 3, lane = e2 & 63;
            int n = 16 * g + (lane & 15);
            int i = 32 * s + 8 * (lane >> 4);
            const float* src = W_in + n * 128 + i;
            bf16x8 vh, vl;
#pragma unroll
            for (int j = 0; j < 8; j++) {
                float w = src[j];
                bf16 h = (bf16)w;
                vh[j] = h;
                vl[j] = (bf16)(w - (float)h);
            }
            WinHi[e2] = vh;
            WinLo[e2] = vl;
        }
    }
}

// ---------------- Phase 1: xproj = x @ W_in^T + b_in (3-term split-bf16) ----------------
// 2000 blocks x 256 threads. Wave handles 2 M-tiles (32 rows of T*B). g processed in pairs;
// each 16x32 f32 result tile is transposed through wave-private LDS so global stores are
// 1KB/instr covering full 128B lines (old version: 4B scatter, 64B partial lines).
__global__ __launch_bounds__(256)
void xproj_kernel(const float* __restrict__ x,
                  const float* __restrict__ b_in,
                  const bf16x8* __restrict__ WinHi,
                  const bf16x8* __restrict__ WinLo,
                  float* __restrict__ out) {
    __shared__ float stg[4][2][16 * 36];   // [wave][tile][16 rows x stride 36] = 18432 B
    const int wave = threadIdx.x >> 6, lane = threadIdx.x & 63;
    const int m = lane & 15, q = lane >> 4;
    const long tile0 = ((long)blockIdx.x * 4 + wave) * 2;

    // x fragments for the wave's 2 tiles (float4 loads + hi/lo bf16 split)
    bf16x8 ah[2][4], al[2][4];
#pragma unroll
    for (int tt = 0; tt < 2; tt++) {
        const floatx4* xr = (const floatx4*)(x + ((tile0 + tt) * 16 + m) * IDIM);
#pragma unroll
        for (int s = 0; s < 4; s++) {
            floatx4 w0 = xr[s * 8 + q * 2];
            floatx4 w1 = xr[s * 8 + q * 2 + 1];
#pragma unroll
            for (int j = 0; j < 4; j++) {
                float a0 = w0[j], a1 = w1[j];
                bf16 h0 = (bf16)a0, h1 = (bf16)a1;
                ah[tt][s][j] = h0;
                ah[tt][s][j + 4] = h1;
                al[tt][s][j] = (bf16)(a0 - (float)h0);
                al[tt][s][j + 4] = (bf16)(a1 - (float)h1);
            }
        }
    }

    const int rrow = lane >> 3;         // 0..7
    const int rcol = (lane & 7) * 4;    // 0,4,..,28

#pragma unroll 2
    for (int gp = 0; gp < 16; gp++) {
        floatx4 acc[2][2];
#pragma unroll
        for (int tt = 0; tt < 2; tt++)
#pragma unroll
            for (int p = 0; p < 2; p++) acc[tt][p] = (floatx4){0.f, 0.f, 0.f, 0.f};

#pragma unroll
        for (int s = 0; s < 4; s++) {
            bf16x8 bh0 = WinHi[((2 * gp) * 4 + s) * 64 + lane];
            bf16x8 bl0 = WinLo[((2 * gp) * 4 + s) * 64 + lane];
            bf16x8 bh1 = WinHi[((2 * gp + 1) * 4 + s) * 64 + lane];
            bf16x8 bl1 = WinLo[((2 * gp + 1) * 4 + s) * 64 + lane];
#pragma unroll
            for (int tt = 0; tt < 2; tt++) {
                acc[tt][0] = __builtin_amdgcn_mfma_f32_16x16x32_bf16(ah[tt][s], bh0, acc[tt][0], 0, 0, 0);
                acc[tt][0] = __builtin_amdgcn_mfma_f32_16x16x32_bf16(al[tt][s], bh0, acc[tt][0], 0, 0, 0);
                acc[tt][0] = __builtin_amdgcn_mfma_f32_16x16x32_bf16(ah[tt][s], bl0, acc[tt][0], 0, 0, 0);
                acc[tt][1] = __builtin_amdgcn_mfma_f32_16x16x32_bf16(ah[tt][s], bh1, acc[tt][1], 0, 0, 0);
                acc[tt][1] = __builtin_amdgcn_mfma_f32_16x16x32_bf16(al[tt][s], bh1, acc[tt][1], 0, 0, 0);
                acc[tt][1] = __builtin_amdgcn_mfma_f32_16x16x32_bf16(ah[tt][s], bl1, acc[tt][1], 0, 0, 0);
            }
        }
        float b0v = b_in[16 * (2 * gp) + m];
        float b1v = b_in[16 * (2 * gp + 1) + m];
        // stage 16x32 tiles to wave-private LDS (D-layout: col=m, row=q*4+r)
#pragma unroll
        for (int tt = 0; tt < 2; tt++) {
            float* T = stg[wave][tt];
#pragma unroll
            for (int r = 0; r < 4; r++) {
                T[(q * 4 + r) * 36 + m] = acc[tt][0][r] + b0v;
                T[(q * 4 + r) * 36 + 16 + m] = acc[tt][1][r] + b1v;
            }
        }
        // read back row-major, store full 128B lines (same-wave lgkm deps auto-waited)
#pragma unroll
        for (int tt = 0; tt < 2; tt++) {
            const float* T = stg[wave][tt];
            long r0 = (tile0 + tt) * 16;
#pragma unroll
            for (int k = 0; k < 2; k++) {
                int row = k * 8 + rrow;
                floatx4 v = *(const floatx4*)(T + row * 36 + rcol);
                *(floatx4*)(out + (r0 + row) * NDIM + 32 * gp + rcol) = v;
            }
        }
    }
}

// ---------------- Phase 2: the sequential scan (8 waves / WG) ----------------
// 16 WGs x 512 threads. WG owns batches [16*blk, 16*blk+16).
// Wave w (0..7) owns n-strips 4w..4w+3 (n = 64w .. 64w+63):
//   strips 4w..4w+2 : W fragments in VGPRs (3*16 bf16x8 = 192 regs/lane)
//   strip  4w+3     : W fragments in LDS slot w (8 strips * 16KB = 128KB)
// pack (LDS, 16KB): pack[s*64+lane] = h_t[b0+(lane&15)][32s + 8*(lane>>4) + j] bf16.
// MFMA: A = W strip rows (M-role = n), B = h frag (N-role = batch).
// D: col(lane&15) = batch m, row = q*4+reg = n within strip.
//
// Barrier discipline (R2): only the pack buffer needs ordering.
//   barrier A (after k-loop, before pack writes): read->write hazard; own ds_reads are
//     already retired via MFMA lgkm waits; lgkmcnt(0) is ~free.
//   barrier B (after pack writes, before next k-loop): write->read hazard; needs lgkmcnt(0).
// Global xp loads / h stores deliberately NOT drained at barriers -- their vmcnt waits
// happen at epilogue use, a full k-loop after issue.
__global__ __launch_bounds__(512, 2)
void scan_kernel(const float* __restrict__ h0,
                 const bf16x8* __restrict__ Whpack,
                 float* __restrict__ out) {
    extern __shared__ char smem[];
    bf16x8* Wlds = (bf16x8*)smem;                    // 8192 entries = 128KB
    bf16x8* pack = (bf16x8*)(smem + 128 * 1024);     // 1024 entries = 16KB

    const int tid = threadIdx.x;
    const int wave = tid >> 6, lane = tid & 63;
    const int m = lane & 15, q = lane >> 4;
    const int b0 = blockIdx.x * 16;

    // --- register-resident W strips: global strips 4w, 4w+1, 4w+2
    bf16x8 Wr[3][16];
    {
        const bf16x8* base = Whpack + (4 * wave) * 1024 + lane;
#pragma unroll
        for (int i = 0; i < 3; i++)
#pragma unroll
            for (int s = 0; s < 16; s++)
                Wr[i][s] = base[(i * 16 + s) * 64];
    }
    // --- cooperative load of LDS strips: slot w <-> global strip 4w+3
    for (int r = 0; r < 16; r++) {
        int e = r * 512 + tid;
        int slot = e >> 10;
        int rem = e & 1023;
        Wlds[e] = Whpack[(4 * slot + 3) * 1024 + rem];
    }
    // --- init canonical h (fp32, regs): wave's 4 strips
    floatx4 h32[4];
#pragma unroll
    for (int i = 0; i < 4; i++) {
        int n0 = (4 * wave + i) * 16 + q * 4;
        h32[i] = *(const floatx4*)(h0 + (b0 + m) * NDIM + n0);
    }
    // --- init bf16 pack from h0 (1024 entries, 512 threads -> 2 each)
    for (int e = tid; e < 1024; e += 512) {
        int s = e >> 6, l = e & 63;
        const float* src = h0 + (b0 + (l & 15)) * NDIM + s * 32 + 8 * (l >> 4);
        bf16x8 v;
#pragma unroll
        for (int j = 0; j < 8; j++) v[j] = (bf16)src[j];
        pack[e] = v;
    }
    __syncthreads();

    const int wslot = wave * 1024;

#pragma unroll 1
    for (int t = 0; t < T_STEPS; t++) {
        float* row = out + ((long)(t * BATCH + b0 + m)) * NDIM;
        // prefetch xp (xproj phase wrote it into out[t]); latency hides under the k-loop
        floatx4 xp[4];
#pragma unroll
        for (int i = 0; i < 4; i++) {
            int n0 = (4 * wave + i) * 16 + q * 4;
            xp[i] = *(const floatx4*)(row + n0);
        }

        floatx4 acc[4];
#pragma unroll
        for (int i = 0; i < 4; i++) acc[i] = (floatx4){0.f, 0.f, 0.f, 0.f};

#pragma unroll
        for (int s = 0; s < 16; s++) {
            bf16x8 hfrag = pack[s * 64 + lane];
#pragma unroll
            for (int i = 0; i < 3; i++)
                acc[i] = __builtin_amdgcn_mfma_f32_16x16x32_bf16(Wr[i][s], hfrag, acc[i], 0, 0, 0);
            bf16x8 wl = Wlds[wslot + s * 64 + lane];
            acc[3] = __builtin_amdgcn_mfma_f32_16x16x32_bf16(wl, hfrag, acc[3], 0, 0, 0);
        }
        // barrier A: all waves done reading pack (h_{t-1}); LDS-only ordering
        asm volatile("s_waitcnt lgkmcnt(0)" ::: "memory");
        __builtin_amdgcn_s_barrier();
        asm volatile("" ::: "memory");

        // epilogue: h_t = 0.8*h + 0.2*tanh(xp + y); pack writes first (they gate barrier B)
#pragma unroll
        for (int i = 0; i < 4; i++) {
            int n0 = (4 * wave + i) * 16 + q * 4;
            floatx4 z = xp[i] + acc[i];
            floatx4 hn;
#pragma unroll
            for (int r = 0; r < 4; r++) {
                // tanh(x) = 1 - 2/(1+exp2(2x*log2 e)); endpoints give +-1 correctly
                float e = __builtin_amdgcn_exp2f(z[r] * 2.885390081777927f);
                hn[r] = 1.0f - 2.0f * __builtin_amdgcn_rcpf(e + 1.0f);
            }
            h32[i] = h32[i] * 0.8f + hn * 0.2f;
            // write 4 bf16 into pack for next step: global k = n0..n0+3
            int sp = n0 >> 5;
            int o = (n0 >> 3) & 3;
            u16x4 pw;
#pragma unroll
            for (int r = 0; r < 4; r++) {
                bf16 hb = (bf16)h32[i][r];
                pw[r] = __builtin_bit_cast(u16, hb);
            }
            *(u16x4*)(((char*)pack) + (sp * 64 + m + 16 * o) * 16 + (n0 & 7) * 2) = pw;
        }
        // barrier B: pack (h_t) visible to all waves before next k-loop
        asm volatile("s_waitcnt lgkmcnt(0)" ::: "memory");
        __builtin_amdgcn_s_barrier();
        asm volatile("" ::: "memory");

        // h_t global store AFTER the barrier: stays out of every wait on the critical path.
        // Non-temporal: h is written once and never re-read on-device -> don't thrash the
        // LLC that the upcoming xp read stream needs.
#pragma unroll
        for (int i = 0; i < 4; i++) {
            int n0 = (4 * wave + i) * 16 + q * 4;
            __builtin_nontemporal_store(h32[i], (floatx4*)(row + n0));
        }
    }

    // final hidden state
    float* hid = out + (long)T_STEPS * BATCH * NDIM;
#pragma unroll
    for (int i = 0; i < 4; i++) {
        int n0 = (4 * wave + i) * 16 + q * 4;
        *(floatx4*)(hid + (b0 + m) * NDIM + n0) = h32[i];
    }
}

extern "C" void kernel_launch(void* const* d_in, const int* in_sizes, int n_in,
                              void* d_out, int out_size, void* d_ws, size_t ws_size,
                              hipStream_t stream) {
    const float* x    = (const float*)d_in[0];
    const float* h0   = (const float*)d_in[1];
    const float* W_in = (const float*)d_in[2];
    const float* b_in = (const float*)d_in[3];
    const float* W_hh = (const float*)d_in[4];
    float* out = (float*)d_out;

    // workspace carve: Whpack 512KB | WinHi 128KB | WinLo 128KB  (total 768KB)
    bf16x8* Whpack = (bf16x8*)d_ws;
    bf16x8* WinHi  = (bf16x8*)((char*)d_ws + 524288);
    bf16x8* WinLo  = (bf16x8*)((char*)d_ws + 655360);

    hipFuncSetAttribute((const void*)scan_kernel,
                        hipFuncAttributeMaxDynamicSharedMemorySize, 147456);

    pack_kernel<<<160, 256, 0, stream>>>(W_hh, W_in, Whpack, WinHi, WinLo);
    xproj_kernel<<<2000, 256, 0, stream>>>(x, b_in, WinHi, WinLo, out);
    scan_kernel<<<16, 512, 147456, stream>>>(h0, Whpack, out);
}